// Round 1
// baseline (235.961 us; speedup 1.0000x reference)
//
#include <hip/hip_runtime.h>
#include <hip/hip_bf16.h>

// Problem constants
constexpr int BB = 8;
constexpr int LLEN = 2048;
constexpr int HH = 256;
constexpr int EE = 512;          // H * EXP
constexpr int MM = BB * LLEN;    // 16384 rows

// ---------------------------------------------------------------------------
// Generic tiled f32 GEMM: C = A[M,K] @ B[K,N] + bias[N]
// 64x64 tile, BK=32, 256 threads, 4x4 acc per thread.
// Split-store: cols < split -> C0, cols >= split -> C1 (col - split).
// ---------------------------------------------------------------------------
__global__ __launch_bounds__(256) void gemm_f32_kernel(
    const float* __restrict__ A, const float* __restrict__ B,
    const float* __restrict__ bias, float* __restrict__ C0, float* __restrict__ C1,
    int M, int N, int K, int ldb, int ldc, int split)
{
    __shared__ float As[32][68];   // [k][m], pad 68 -> 16B-aligned rows, b128 reads
    __shared__ float Bs[32][64];   // [k][n]

    const int tid = threadIdx.x;
    const int tx = tid & 15;       // 0..15 -> 4 cols each
    const int ty = tid >> 4;       // 0..15 -> 4 rows each
    const int row0 = blockIdx.y * 64;
    const int col0 = blockIdx.x * 64;

    float acc[4][4] = {};

    for (int kt = 0; kt < K; kt += 32) {
        // stage A tile: 64 rows x 32 k  (global k-contiguous)
        #pragma unroll
        for (int r = 0; r < 8; ++r) {
            int idx = tid + r * 256;
            int m = idx >> 5, k = idx & 31;
            As[k][m] = A[(size_t)(row0 + m) * K + (kt + k)];
        }
        // stage B tile: 32 k x 64 n
        #pragma unroll
        for (int r = 0; r < 8; ++r) {
            int idx = tid + r * 256;
            int k = idx >> 6, n = idx & 63;
            Bs[k][n] = B[(size_t)(kt + k) * ldb + (col0 + n)];
        }
        __syncthreads();

        #pragma unroll
        for (int ks = 0; ks < 32; ++ks) {
            float4 av = *reinterpret_cast<const float4*>(&As[ks][ty * 4]);
            float4 bv = *reinterpret_cast<const float4*>(&Bs[ks][tx * 4]);
            float a[4] = {av.x, av.y, av.z, av.w};
            float b[4] = {bv.x, bv.y, bv.z, bv.w};
            #pragma unroll
            for (int i = 0; i < 4; ++i)
                #pragma unroll
                for (int j = 0; j < 4; ++j)
                    acc[i][j] = fmaf(a[i], b[j], acc[i][j]);
        }
        __syncthreads();
    }

    // epilogue: bias + split store
    #pragma unroll
    for (int i = 0; i < 4; ++i) {
        int m = row0 + ty * 4 + i;
        #pragma unroll
        for (int j = 0; j < 4; ++j) {
            int n = col0 + tx * 4 + j;
            float v = acc[i][j] + bias[n];
            if (n < split) C0[(size_t)m * ldc + n] = v;
            else           C1[(size_t)m * ldc + (n - split)] = v;
        }
    }
}

// ---------------------------------------------------------------------------
// Fused middle: depthwise conv(k=3,pad=1 along L) + SiLU + Dp* + LayerNorm(E)
//               + *silu(z).  One block per (b,l) row; gbuf written in place
//               over z (each element read+written by the same thread).
// Key algebraic fact: the SSM scan output is constant over E (h0=0, input
// term broadcasts over E), so LayerNorm cancels it exactly -> skipped.
// ---------------------------------------------------------------------------
__global__ __launch_bounds__(256) void mid_kernel(
    const float* __restrict__ x_raw, float* __restrict__ zg,
    const float* __restrict__ conv_w, const float* __restrict__ conv_b,
    const float* __restrict__ Dp, const float* __restrict__ ln_g,
    const float* __restrict__ ln_b)
{
    const int row = blockIdx.x;          // b*L + l
    const int l = row & (LLEN - 1);
    const int tid = threadIdx.x;
    const float* base = x_raw + (size_t)row * EE;

    float o[2];
    float s1 = 0.f, s2 = 0.f;
    #pragma unroll
    for (int r = 0; r < 2; ++r) {
        int e = tid + r * 256;
        float w0 = conv_w[e * 3 + 0];
        float w1 = conv_w[e * 3 + 1];
        float w2 = conv_w[e * 3 + 2];
        float v = conv_b[e] + base[e] * w1;
        if (l > 0)        v += base[e - EE] * w0;
        if (l < LLEN - 1) v += base[e + EE] * w2;
        float sx = v / (1.f + __expf(-v));   // silu
        float oe = Dp[e] * sx;
        o[r] = oe;
        s1 += oe;
        s2 += oe * oe;
    }

    // block reduction over 512 elems (4 waves of 64)
    __shared__ float red[2][4];
    #pragma unroll
    for (int off = 32; off > 0; off >>= 1) {
        s1 += __shfl_down(s1, off);
        s2 += __shfl_down(s2, off);
    }
    int wid = tid >> 6, lane = tid & 63;
    if (lane == 0) { red[0][wid] = s1; red[1][wid] = s2; }
    __syncthreads();
    float S1 = red[0][0] + red[0][1] + red[0][2] + red[0][3];
    float S2 = red[1][0] + red[1][1] + red[1][2] + red[1][3];

    const float mu  = S1 * (1.f / EE);
    const float var = S2 * (1.f / EE) - mu * mu;
    const float inv = rsqrtf(var + 1e-5f);

    #pragma unroll
    for (int r = 0; r < 2; ++r) {
        int e = tid + r * 256;
        size_t idx = (size_t)row * EE + e;
        float zn = zg[idx];
        float sz = zn / (1.f + __expf(-zn));
        zg[idx] = ((o[r] - mu) * inv * ln_g[e] + ln_b[e]) * sz;
    }
}

// ---------------------------------------------------------------------------
extern "C" void kernel_launch(void* const* d_in, const int* in_sizes, int n_in,
                              void* d_out, int out_size, void* d_ws, size_t ws_size,
                              hipStream_t stream)
{
    const float* u      = (const float*)d_in[0];
    const float* W_in   = (const float*)d_in[1];
    const float* b_in   = (const float*)d_in[2];
    const float* conv_w = (const float*)d_in[3];
    const float* conv_b = (const float*)d_in[4];
    // d_in[5]=W_x, d_in[6]=b_x, d_in[7]=A_log: dead (scan cancels under LN)
    const float* Dp     = (const float*)d_in[8];
    const float* W_out  = (const float*)d_in[9];
    const float* b_out  = (const float*)d_in[10];
    const float* ln_g   = (const float*)d_in[11];
    const float* ln_b   = (const float*)d_in[12];
    float* out = (float*)d_out;

    float* x_raw = (float*)d_ws;                 // [M, E]
    float* zg    = x_raw + (size_t)MM * EE;      // [M, E], z then reused as gbuf

    dim3 blk(256);

    // K1: xz = u @ W_in + b_in ; split cols [0,512)->x_raw, [512,1024)->z
    gemm_f32_kernel<<<dim3(1024 / 64, MM / 64), blk, 0, stream>>>(
        u, W_in, b_in, x_raw, zg, MM, 1024, HH, 1024, EE, EE);

    // K2: conv+silu+Dp*+LN+silu(z) -> gbuf (in place over z)
    mid_kernel<<<dim3(MM), blk, 0, stream>>>(
        x_raw, zg, conv_w, conv_b, Dp, ln_g, ln_b);

    // K3: out = gbuf @ W_out + b_out
    gemm_f32_kernel<<<dim3(HH / 64, MM / 64), blk, 0, stream>>>(
        zg, W_out, b_out, out, out, MM, HH, EE, HH, HH, 1 << 30);
}

// Round 2
// 86.984 us; speedup vs baseline: 2.7127x; 2.7127x over previous
//
#include <hip/hip_runtime.h>
#include <hip/hip_bf16.h>

// Problem constants
constexpr int BB = 8;
constexpr int LLEN = 2048;
constexpr int HH = 256;
constexpr int EE = 512;          // H * EXP
constexpr int MM = BB * LLEN;    // 16384 rows

typedef short bf16x8 __attribute__((ext_vector_type(8)));
typedef float f32x4  __attribute__((ext_vector_type(4)));

static __device__ inline unsigned short f2bf(float f) {
    unsigned u = __builtin_bit_cast(unsigned, f);
    unsigned r = (u + 0x7FFFu + ((u >> 16) & 1u)) >> 16;
    return (unsigned short)r;
}

#define GL2LDS(gp, lp) __builtin_amdgcn_global_load_lds( \
    (const __attribute__((address_space(1))) void*)(gp), \
    (__attribute__((address_space(3))) void*)(lp), 16, 0, 0)

// ---------------------------------------------------------------------------
// cast f32 -> bf16, 4 elems/thread (n must be multiple of 1024)
// ---------------------------------------------------------------------------
__global__ __launch_bounds__(256) void cast_bf16_kernel(
    const float* __restrict__ in, unsigned short* __restrict__ out)
{
    int i = (blockIdx.x * 256 + threadIdx.x) * 4;
    float4 v = *reinterpret_cast<const float4*>(in + i);
    ushort4 o = {f2bf(v.x), f2bf(v.y), f2bf(v.z), f2bf(v.w)};
    *reinterpret_cast<ushort4*>(out + i) = o;
}

// ---------------------------------------------------------------------------
// Wt[n][k] = (bf16) W[k][n]   (output-contiguous)
// ---------------------------------------------------------------------------
__global__ __launch_bounds__(256) void transpose_cast_kernel(
    const float* __restrict__ W, unsigned short* __restrict__ Wt, int K, int N)
{
    int i = blockIdx.x * 256 + threadIdx.x;
    if (i < K * N) {
        int n = i / K, k = i - n * K;
        Wt[i] = f2bf(W[(size_t)k * N + n]);
    }
}

// ---------------------------------------------------------------------------
// bf16 MFMA GEMM: C = A[M,K]bf16 @ Bt[N,K]bf16^T + bias, f32 out, split store.
// 128x128 tile, BK=32, 256 thr = 4 waves (2x2), wave tile 64x64 = 4x4 frags
// of mfma_f32_16x16x32_bf16. global_load_lds w=16; XOR-swizzled LDS:
// 16B slot s at row r holds k-group (s ^ ((r>>1)&3))  [pre-swizzled global
// source + matching XOR on ds_read -> 2-way (free) bank access].
// ---------------------------------------------------------------------------
template<int K>
__global__ __launch_bounds__(256) void gemm_bf16_mfma(
    const unsigned short* __restrict__ A, const unsigned short* __restrict__ Bt,
    const float* __restrict__ bias, float* __restrict__ C0, float* __restrict__ C1,
    int split, int ldc0, int ldc1)
{
    __shared__ unsigned short Al[128 * 32];
    __shared__ unsigned short Bl[128 * 32];

    const int tid = threadIdx.x;
    const int lane = tid & 63;
    const int wave = tid >> 6;
    const int wrow = wave >> 1, wcol = wave & 1;
    const int row0 = blockIdx.y * 128;
    const int col0 = blockIdx.x * 128;

    const int l15 = lane & 15;
    const int lk  = lane >> 4;                 // k16 group 0..3
    const int swz = (l15 >> 1) & 3;
    // ds_read offsets (ushort units): row*32 + swizzled k16*8
    const int aoff = (wrow * 64 + l15) * 32 + ((lk ^ swz) << 3);
    const int boff = (wcol * 64 + l15) * 32 + ((lk ^ swz) << 3);

    f32x4 acc[4][4] = {};

    for (int kt = 0; kt < K; kt += 32) {
        #pragma unroll
        for (int q = 0; q < 2; ++q) {
            int id = q * 256 + tid;
            int r = id >> 2, s = id & 3;
            int ksw = kt + (((s ^ ((r >> 1) & 3)) << 3));
            GL2LDS(A + (size_t)(row0 + r) * K + ksw, &Al[id * 8]);
        }
        #pragma unroll
        for (int q = 0; q < 2; ++q) {
            int id = q * 256 + tid;
            int r = id >> 2, s = id & 3;
            int ksw = kt + (((s ^ ((r >> 1) & 3)) << 3));
            GL2LDS(Bt + (size_t)(col0 + r) * K + ksw, &Bl[id * 8]);
        }
        __syncthreads();

        bf16x8 af[4], bfr[4];
        #pragma unroll
        for (int m = 0; m < 4; ++m)
            af[m] = *reinterpret_cast<const bf16x8*>(&Al[aoff + m * 512]);
        #pragma unroll
        for (int n = 0; n < 4; ++n)
            bfr[n] = *reinterpret_cast<const bf16x8*>(&Bl[boff + n * 512]);
        #pragma unroll
        for (int m = 0; m < 4; ++m)
            #pragma unroll
            for (int n = 0; n < 4; ++n)
                acc[m][n] = __builtin_amdgcn_mfma_f32_16x16x32_bf16(
                    af[m], bfr[n], acc[m][n], 0, 0, 0);
        __syncthreads();
    }

    // epilogue: C/D layout col = lane&15, row = (lane>>4)*4 + i
    #pragma unroll
    for (int m = 0; m < 4; ++m) {
        #pragma unroll
        for (int n = 0; n < 4; ++n) {
            int col = col0 + wcol * 64 + n * 16 + l15;
            float bv = bias[col];
            #pragma unroll
            for (int i = 0; i < 4; ++i) {
                int row = row0 + wrow * 64 + m * 16 + lk * 4 + i;
                float v = acc[m][n][i] + bv;
                if (col < split) C0[(size_t)row * ldc0 + col] = v;
                else             C1[(size_t)row * ldc1 + (col - split)] = v;
            }
        }
    }
}

// ---------------------------------------------------------------------------
// Fused middle: depthwise conv(k=3,pad=1 along L) + SiLU + Dp* + LayerNorm(E)
//               + *silu(z)  -> gbuf (bf16, feeds K3).
// SSM scan output is constant over E (h0=0, input term broadcasts over E),
// so LayerNorm cancels it exactly -> skipped. W_x/b_x/A_log are dead inputs.
// ---------------------------------------------------------------------------
__global__ __launch_bounds__(256) void mid_kernel(
    const float* __restrict__ x_raw, const float* __restrict__ z,
    unsigned short* __restrict__ gbuf,
    const float* __restrict__ conv_w, const float* __restrict__ conv_b,
    const float* __restrict__ Dp, const float* __restrict__ ln_g,
    const float* __restrict__ ln_b)
{
    const int row = blockIdx.x;          // b*L + l
    const int l = row & (LLEN - 1);
    const int tid = threadIdx.x;
    const float* base = x_raw + (size_t)row * EE;

    float o[2];
    float s1 = 0.f, s2 = 0.f;
    #pragma unroll
    for (int r = 0; r < 2; ++r) {
        int e = tid + r * 256;
        float w0 = conv_w[e * 3 + 0];
        float w1 = conv_w[e * 3 + 1];
        float w2 = conv_w[e * 3 + 2];
        float v = conv_b[e] + base[e] * w1;
        if (l > 0)        v += base[e - EE] * w0;
        if (l < LLEN - 1) v += base[e + EE] * w2;
        float sx = v / (1.f + __expf(-v));   // silu
        float oe = Dp[e] * sx;
        o[r] = oe;
        s1 += oe;
        s2 += oe * oe;
    }

    __shared__ float red[2][4];
    #pragma unroll
    for (int off = 32; off > 0; off >>= 1) {
        s1 += __shfl_down(s1, off);
        s2 += __shfl_down(s2, off);
    }
    int wid = tid >> 6, lane = tid & 63;
    if (lane == 0) { red[0][wid] = s1; red[1][wid] = s2; }
    __syncthreads();
    float S1 = red[0][0] + red[0][1] + red[0][2] + red[0][3];
    float S2 = red[1][0] + red[1][1] + red[1][2] + red[1][3];

    const float mu  = S1 * (1.f / EE);
    const float var = S2 * (1.f / EE) - mu * mu;
    const float inv = rsqrtf(var + 1e-5f);

    #pragma unroll
    for (int r = 0; r < 2; ++r) {
        int e = tid + r * 256;
        size_t idx = (size_t)row * EE + e;
        float zn = z[idx];
        float sz = zn / (1.f + __expf(-zn));
        gbuf[idx] = f2bf(((o[r] - mu) * inv * ln_g[e] + ln_b[e]) * sz);
    }
}

// ---------------------------------------------------------------------------
extern "C" void kernel_launch(void* const* d_in, const int* in_sizes, int n_in,
                              void* d_out, int out_size, void* d_ws, size_t ws_size,
                              hipStream_t stream)
{
    const float* u      = (const float*)d_in[0];
    const float* W_in   = (const float*)d_in[1];
    const float* b_in   = (const float*)d_in[2];
    const float* conv_w = (const float*)d_in[3];
    const float* conv_b = (const float*)d_in[4];
    // d_in[5]=W_x, d_in[6]=b_x, d_in[7]=A_log: dead (scan cancels under LN)
    const float* Dp     = (const float*)d_in[8];
    const float* W_out  = (const float*)d_in[9];
    const float* b_out  = (const float*)d_in[10];
    const float* ln_g   = (const float*)d_in[11];
    const float* ln_b   = (const float*)d_in[12];
    float* out = (float*)d_out;

    // workspace carve-up
    char* ws = (char*)d_ws;
    unsigned short* ubf   = (unsigned short*)ws;                    ws += (size_t)MM * HH * 2;   // 8.4MB
    unsigned short* wtin  = (unsigned short*)ws;                    ws += (size_t)1024 * HH * 2; // 0.5MB
    unsigned short* wtout = (unsigned short*)ws;                    ws += (size_t)HH * EE * 2;   // 0.25MB
    float*          x_raw = (float*)ws;                             ws += (size_t)MM * EE * 4;   // 33.5MB
    float*          zbuf  = (float*)ws;                             ws += (size_t)MM * EE * 4;   // 33.5MB
    unsigned short* gbuf  = (unsigned short*)ws;                                                 // 16.8MB

    dim3 blk(256);

    // prep: casts + weight transposes
    cast_bf16_kernel<<<dim3(MM * HH / 1024), blk, 0, stream>>>(u, ubf);
    transpose_cast_kernel<<<dim3((1024 * HH + 255) / 256), blk, 0, stream>>>(W_in, wtin, HH, 1024);
    transpose_cast_kernel<<<dim3((HH * EE + 255) / 256), blk, 0, stream>>>(W_out, wtout, EE, HH);

    // K1: xz = u @ W_in + b_in ; cols [0,512)->x_raw, [512,1024)->z
    gemm_bf16_mfma<HH><<<dim3(1024 / 128, MM / 128), blk, 0, stream>>>(
        ubf, wtin, b_in, x_raw, zbuf, EE, EE, EE);

    // K2: conv+silu+Dp*+LN+silu(z) -> gbuf bf16
    mid_kernel<<<dim3(MM), blk, 0, stream>>>(
        x_raw, zbuf, gbuf, conv_w, conv_b, Dp, ln_g, ln_b);

    // K3: out = gbuf @ W_out + b_out
    gemm_bf16_mfma<EE><<<dim3(HH / 128, MM / 128), blk, 0, stream>>>(
        gbuf, wtout, b_out, out, out, 1 << 30, HH, HH);
}

// Round 3
// 72.038 us; speedup vs baseline: 3.2755x; 1.2075x over previous
//
#include <hip/hip_runtime.h>
#include <hip/hip_bf16.h>

// Problem constants
constexpr int BB = 8;
constexpr int LLEN = 2048;
constexpr int HH = 256;
constexpr int EE = 512;          // H * EXP
constexpr int MM = BB * LLEN;    // 16384 rows

typedef short bf16x8 __attribute__((ext_vector_type(8)));
typedef float f32x4  __attribute__((ext_vector_type(4)));

static __device__ inline unsigned short f2bf(float f) {
    unsigned u = __builtin_bit_cast(unsigned, f);
    unsigned r = (u + 0x7FFFu + ((u >> 16) & 1u)) >> 16;
    return (unsigned short)r;
}
static __device__ inline float bf2f(unsigned short h) {
    return __builtin_bit_cast(float, (unsigned)h << 16);
}

#define GL2LDS(gp, lp) __builtin_amdgcn_global_load_lds( \
    (const __attribute__((address_space(1))) void*)(gp), \
    (__attribute__((address_space(3))) void*)(lp), 16, 0, 0)

// ---------------------------------------------------------------------------
// cast f32 -> bf16, 4 elems/thread (n must be multiple of 1024)
// ---------------------------------------------------------------------------
__global__ __launch_bounds__(256) void cast_bf16_kernel(
    const float* __restrict__ in, unsigned short* __restrict__ out)
{
    int i = (blockIdx.x * 256 + threadIdx.x) * 4;
    float4 v = *reinterpret_cast<const float4*>(in + i);
    ushort4 o = {f2bf(v.x), f2bf(v.y), f2bf(v.z), f2bf(v.w)};
    *reinterpret_cast<ushort4*>(out + i) = o;
}

// ---------------------------------------------------------------------------
// Wt[n][k] = (bf16) W[k][n]   (output-contiguous)
// ---------------------------------------------------------------------------
__global__ __launch_bounds__(256) void transpose_cast_kernel(
    const float* __restrict__ W, unsigned short* __restrict__ Wt, int K, int N)
{
    int i = blockIdx.x * 256 + threadIdx.x;
    if (i < K * N) {
        int n = i / K, k = i - n * K;
        Wt[i] = f2bf(W[(size_t)k * N + n]);
    }
}

// ---------------------------------------------------------------------------
// bf16 MFMA GEMM: C = A[M,K]bf16 @ Bt[N,K]bf16^T + bias, split store.
// 128x128 tile, BK=32, 256 thr = 4 waves (2x2), wave tile 64x64 = 4x4 frags
// of mfma_f32_16x16x32_bf16. global_load_lds w=16; XOR-swizzled LDS
// (pre-swizzled global source + matching XOR on ds_read).
// BF16OUT: store outputs as bf16 (else f32). SILU1: apply SiLU to C1 cols.
// ---------------------------------------------------------------------------
template<int K, bool BF16OUT, bool SILU1>
__global__ __launch_bounds__(256) void gemm_bf16_mfma(
    const unsigned short* __restrict__ A, const unsigned short* __restrict__ Bt,
    const float* __restrict__ bias, void* __restrict__ C0v, void* __restrict__ C1v,
    int split, int ldc0, int ldc1)
{
    __shared__ unsigned short Al[128 * 32];
    __shared__ unsigned short Bl[128 * 32];

    const int tid = threadIdx.x;
    const int lane = tid & 63;
    const int wave = tid >> 6;
    const int wrow = wave >> 1, wcol = wave & 1;
    const int row0 = blockIdx.y * 128;
    const int col0 = blockIdx.x * 128;

    const int l15 = lane & 15;
    const int lk  = lane >> 4;                 // k16 group 0..3
    const int swz = (l15 >> 1) & 3;
    const int aoff = (wrow * 64 + l15) * 32 + ((lk ^ swz) << 3);
    const int boff = (wcol * 64 + l15) * 32 + ((lk ^ swz) << 3);

    f32x4 acc[4][4] = {};

    for (int kt = 0; kt < K; kt += 32) {
        #pragma unroll
        for (int q = 0; q < 2; ++q) {
            int id = q * 256 + tid;
            int r = id >> 2, s = id & 3;
            int ksw = kt + (((s ^ ((r >> 1) & 3)) << 3));
            GL2LDS(A + (size_t)(row0 + r) * K + ksw, &Al[id * 8]);
        }
        #pragma unroll
        for (int q = 0; q < 2; ++q) {
            int id = q * 256 + tid;
            int r = id >> 2, s = id & 3;
            int ksw = kt + (((s ^ ((r >> 1) & 3)) << 3));
            GL2LDS(Bt + (size_t)(col0 + r) * K + ksw, &Bl[id * 8]);
        }
        __syncthreads();

        bf16x8 af[4], bfr[4];
        #pragma unroll
        for (int m = 0; m < 4; ++m)
            af[m] = *reinterpret_cast<const bf16x8*>(&Al[aoff + m * 512]);
        #pragma unroll
        for (int n = 0; n < 4; ++n)
            bfr[n] = *reinterpret_cast<const bf16x8*>(&Bl[boff + n * 512]);
        #pragma unroll
        for (int m = 0; m < 4; ++m)
            #pragma unroll
            for (int n = 0; n < 4; ++n)
                acc[m][n] = __builtin_amdgcn_mfma_f32_16x16x32_bf16(
                    af[m], bfr[n], acc[m][n], 0, 0, 0);
        __syncthreads();
    }

    // epilogue: C/D layout col = lane&15, row = (lane>>4)*4 + i
    #pragma unroll
    for (int m = 0; m < 4; ++m) {
        #pragma unroll
        for (int n = 0; n < 4; ++n) {
            int col = col0 + wcol * 64 + n * 16 + l15;
            float bv = bias[col];
            #pragma unroll
            for (int i = 0; i < 4; ++i) {
                int row = row0 + wrow * 64 + m * 16 + lk * 4 + i;
                float v = acc[m][n][i] + bv;
                if (col < split) {
                    if (BF16OUT)
                        ((unsigned short*)C0v)[(size_t)row * ldc0 + col] = f2bf(v);
                    else
                        ((float*)C0v)[(size_t)row * ldc0 + col] = v;
                } else {
                    float w = SILU1 ? (v / (1.f + __expf(-v))) : v;
                    if (BF16OUT)
                        ((unsigned short*)C1v)[(size_t)row * ldc1 + (col - split)] = f2bf(w);
                    else
                        ((float*)C1v)[(size_t)row * ldc1 + (col - split)] = w;
                }
            }
        }
    }
}

// ---------------------------------------------------------------------------
// Fused middle: depthwise conv(k=3,pad=1 along L) + SiLU + Dp* + LayerNorm(E)
//               + *silu(z)  -> gbuf (bf16, feeds K3).
// Wave-per-row: 64 lanes x 8 contiguous e = 512 = E. 4 rows per block.
// SSM scan output is constant over E (h0=0, input term broadcasts over E),
// so LayerNorm cancels it exactly -> skipped. W_x/b_x/A_log are dead inputs.
// ---------------------------------------------------------------------------
__global__ __launch_bounds__(256) void mid_kernel(
    const unsigned short* __restrict__ x, const unsigned short* __restrict__ zs,
    unsigned short* __restrict__ g,
    const float* __restrict__ conv_w, const float* __restrict__ conv_b,
    const float* __restrict__ Dp, const float* __restrict__ ln_g,
    const float* __restrict__ ln_b)
{
    const int lane = threadIdx.x & 63;
    const int wid  = threadIdx.x >> 6;
    const int row  = blockIdx.x * 4 + wid;     // b*L + l
    const int l    = row & (LLEN - 1);
    const int e0   = lane * 8;
    const size_t base = (size_t)row * EE + e0;

    bf16x8 xc = *reinterpret_cast<const bf16x8*>(x + base);
    bf16x8 xm = {}, xp = {};
    if (l > 0)        xm = *reinterpret_cast<const bf16x8*>(x + base - EE);
    if (l < LLEN - 1) xp = *reinterpret_cast<const bf16x8*>(x + base + EE);

    float o[8];
    float s1 = 0.f, s2 = 0.f;
    #pragma unroll
    for (int j = 0; j < 8; ++j) {
        int e = e0 + j;
        float v = conv_b[e]
                + bf2f((unsigned short)xm[j]) * conv_w[e * 3 + 0]
                + bf2f((unsigned short)xc[j]) * conv_w[e * 3 + 1]
                + bf2f((unsigned short)xp[j]) * conv_w[e * 3 + 2];
        float sx = v / (1.f + __expf(-v));   // silu
        float oe = Dp[e] * sx;
        o[j] = oe;
        s1 += oe;
        s2 += oe * oe;
    }

    // full-wave butterfly reduce (all lanes get the sums)
    #pragma unroll
    for (int off = 1; off < 64; off <<= 1) {
        s1 += __shfl_xor(s1, off);
        s2 += __shfl_xor(s2, off);
    }

    const float mu  = s1 * (1.f / EE);
    const float var = s2 * (1.f / EE) - mu * mu;
    const float inv = rsqrtf(var + 1e-5f);

    bf16x8 zv = *reinterpret_cast<const bf16x8*>(zs + base);
    bf16x8 ov;
    #pragma unroll
    for (int j = 0; j < 8; ++j) {
        int e = e0 + j;
        float gy = ((o[j] - mu) * inv * ln_g[e] + ln_b[e]) * bf2f((unsigned short)zv[j]);
        ov[j] = (short)f2bf(gy);
    }
    *reinterpret_cast<bf16x8*>(g + base) = ov;
}

// ---------------------------------------------------------------------------
extern "C" void kernel_launch(void* const* d_in, const int* in_sizes, int n_in,
                              void* d_out, int out_size, void* d_ws, size_t ws_size,
                              hipStream_t stream)
{
    const float* u      = (const float*)d_in[0];
    const float* W_in   = (const float*)d_in[1];
    const float* b_in   = (const float*)d_in[2];
    const float* conv_w = (const float*)d_in[3];
    const float* conv_b = (const float*)d_in[4];
    // d_in[5]=W_x, d_in[6]=b_x, d_in[7]=A_log: dead (scan cancels under LN)
    const float* Dp     = (const float*)d_in[8];
    const float* W_out  = (const float*)d_in[9];
    const float* b_out  = (const float*)d_in[10];
    const float* ln_g   = (const float*)d_in[11];
    const float* ln_b   = (const float*)d_in[12];
    float* out = (float*)d_out;

    // workspace carve-up (all bf16 intermediates)
    char* ws = (char*)d_ws;
    unsigned short* ubf   = (unsigned short*)ws; ws += (size_t)MM * HH * 2;    // 8.4MB
    unsigned short* wtin  = (unsigned short*)ws; ws += (size_t)1024 * HH * 2;  // 0.5MB
    unsigned short* wtout = (unsigned short*)ws; ws += (size_t)HH * EE * 2;    // 0.25MB
    unsigned short* xbuf  = (unsigned short*)ws; ws += (size_t)MM * EE * 2;    // 16.8MB
    unsigned short* zsbuf = (unsigned short*)ws; ws += (size_t)MM * EE * 2;    // 16.8MB  silu(z)
    unsigned short* gbuf  = (unsigned short*)ws;                               // 16.8MB

    dim3 blk(256);

    // prep: casts + weight transposes
    cast_bf16_kernel<<<dim3(MM * HH / 1024), blk, 0, stream>>>(u, ubf);
    transpose_cast_kernel<<<dim3((1024 * HH + 255) / 256), blk, 0, stream>>>(W_in, wtin, HH, 1024);
    transpose_cast_kernel<<<dim3((HH * EE + 255) / 256), blk, 0, stream>>>(W_out, wtout, EE, HH);

    // K1: xz = u @ W_in + b_in ; cols [0,512)->x bf16, [512,1024)->silu(z) bf16
    gemm_bf16_mfma<HH, true, true><<<dim3(1024 / 128, MM / 128), blk, 0, stream>>>(
        ubf, wtin, b_in, xbuf, zsbuf, EE, EE, EE);

    // K2: conv+silu+Dp*+LN+*silu(z) -> gbuf bf16
    mid_kernel<<<dim3(MM / 4), blk, 0, stream>>>(
        xbuf, zsbuf, gbuf, conv_w, conv_b, Dp, ln_g, ln_b);

    // K3: out = gbuf @ W_out + b_out (f32 out)
    gemm_bf16_mfma<EE, false, false><<<dim3(HH / 128, MM / 128), blk, 0, stream>>>(
        gbuf, wtout, b_out, out, out, 1 << 30, HH, HH);
}

// Round 4
// 62.540 us; speedup vs baseline: 3.7730x; 1.1519x over previous
//
#include <hip/hip_runtime.h>
#include <hip/hip_bf16.h>

// Problem constants
constexpr int BB = 8;
constexpr int LLEN = 2048;
constexpr int HH = 256;
constexpr int EE = 512;          // H * EXP
constexpr int MM = BB * LLEN;    // 16384 rows

typedef short bf16x8 __attribute__((ext_vector_type(8)));
typedef float f32x4  __attribute__((ext_vector_type(4)));

static __device__ inline unsigned short f2bf(float f) {
    unsigned u = __builtin_bit_cast(unsigned, f);
    unsigned r = (u + 0x7FFFu + ((u >> 16) & 1u)) >> 16;
    return (unsigned short)r;
}
static __device__ inline float bf2f(unsigned short h) {
    return __builtin_bit_cast(float, (unsigned)h << 16);
}

#define GL2LDS(gp, lp) __builtin_amdgcn_global_load_lds( \
    (const __attribute__((address_space(1))) void*)(gp), \
    (__attribute__((address_space(3))) void*)(lp), 16, 0, 0)

// ---------------------------------------------------------------------------
// cast f32 -> bf16, 4 elems/thread; XCD-swizzled so rows chain into K1's L2.
// ---------------------------------------------------------------------------
__global__ __launch_bounds__(256) void cast_bf16_kernel(
    const float* __restrict__ in, unsigned short* __restrict__ out)
{
    int b = blockIdx.x;
    int cpx = gridDim.x >> 3;
    int lin = (b & 7) * cpx + (b >> 3);
    int i = (lin * 256 + threadIdx.x) * 4;
    float4 v = *reinterpret_cast<const float4*>(in + i);
    ushort4 o = {f2bf(v.x), f2bf(v.y), f2bf(v.z), f2bf(v.w)};
    *reinterpret_cast<ushort4*>(out + i) = o;
}

// ---------------------------------------------------------------------------
// Wt[n][k] = (bf16) W[k][n]   (output-contiguous)
// ---------------------------------------------------------------------------
__global__ __launch_bounds__(256) void transpose_cast_kernel(
    const float* __restrict__ W, unsigned short* __restrict__ Wt, int K, int N)
{
    int i = blockIdx.x * 256 + threadIdx.x;
    if (i < K * N) {
        int n = i / K, k = i - n * K;
        Wt[i] = f2bf(W[(size_t)k * N + n]);
    }
}

// ---------------------------------------------------------------------------
// bf16 MFMA GEMM, 2-phase double-buffered pipeline with counted vmcnt (T3+T4).
// C = A[M,K]bf16 @ Bt[N,K]bf16^T + bias, split store.
// Tile BM x BN, BK=64, 256 thr = 4 waves; wave tile (MFR*16) x (NFR*16).
// LDS XOR swizzle: 16B slot s of row r stored at s^(r&7) (pre-swizzled
// global source for global_load_lds + same XOR on ds_read).
// XCD-chunk blockIdx swizzle (grid % 8 == 0).
// ---------------------------------------------------------------------------
template<int BM, int BN, int K, int MFR, int NFR, int GX, bool BF16OUT, bool SILU1>
__global__ __launch_bounds__(256) void gemm2(
    const unsigned short* __restrict__ A, const unsigned short* __restrict__ Bt,
    const float* __restrict__ bias, void* __restrict__ C0v, void* __restrict__ C1v,
    int split, int ldc0, int ldc1)
{
    constexpr int BK = 64;
    constexpr int NT = K / BK;
    constexpr int AL = BM * 8 / 256;   // gload_lds per thread, A tile
    constexpr int BL = BN * 8 / 256;   // gload_lds per thread, B tile
    constexpr int NL = AL + BL;        // loads per stage (vmcnt quantum)
    constexpr int WCOLS = BN / (16 * NFR);

    __shared__ unsigned short Al[2][BM * BK];
    __shared__ unsigned short Bl[2][BN * BK];

    const int tid = threadIdx.x;
    const int lane = tid & 63;
    const int wave = tid >> 6;
    const int wrow = wave / WCOLS, wcol = wave % WCOLS;
    const int l15 = lane & 15;
    const int lk  = lane >> 4;

    // XCD-chunk swizzle (bijective since grid % 8 == 0)
    const int cpx = gridDim.x >> 3;
    int lin = blockIdx.x;
    lin = (lin & 7) * cpx + (lin >> 3);
    const int row0 = (lin / GX) * BM;
    const int col0 = (lin % GX) * BN;

    f32x4 acc[MFR][NFR] = {};

    auto stage = [&](int bi, int kt) {
        const unsigned short* Ab = A + (size_t)row0 * K + kt;
        #pragma unroll
        for (int i = 0; i < AL; ++i) {
            int sid = i * 256 + tid;
            int r = sid >> 3, sl = sid & 7;
            GL2LDS(Ab + (size_t)r * K + ((sl ^ (r & 7)) << 3), &Al[bi][sid * 8]);
        }
        const unsigned short* Bb = Bt + (size_t)col0 * K + kt;
        #pragma unroll
        for (int i = 0; i < BL; ++i) {
            int sid = i * 256 + tid;
            int r = sid >> 3, sl = sid & 7;
            GL2LDS(Bb + (size_t)r * K + ((sl ^ (r & 7)) << 3), &Bl[bi][sid * 8]);
        }
    };

    stage(0, 0);   // prologue: tile 0 loads in flight

    #pragma unroll
    for (int t = 0; t < NT; ++t) {
        const int bi = t & 1;
        if (t + 1 < NT) {
            stage(bi ^ 1, (t + 1) * BK);   // issue next tile (stays in flight)
            asm volatile("s_waitcnt vmcnt(%0)" :: "n"(NL) : "memory");
        } else {
            asm volatile("s_waitcnt vmcnt(0)" ::: "memory");
        }
        __builtin_amdgcn_sched_barrier(0);
        __builtin_amdgcn_s_barrier();      // tile t fully staged (all waves)

        bf16x8 af[MFR][2], bfr[NFR][2];
        #pragma unroll
        for (int m = 0; m < MFR; ++m) {
            const int r = wrow * (MFR * 16) + m * 16 + l15;
            #pragma unroll
            for (int kk = 0; kk < 2; ++kk) {
                const int sl = (kk * 4 + lk) ^ (r & 7);
                af[m][kk] = *reinterpret_cast<const bf16x8*>(&Al[bi][r * 64 + sl * 8]);
            }
        }
        #pragma unroll
        for (int n = 0; n < NFR; ++n) {
            const int r = wcol * (NFR * 16) + n * 16 + l15;
            #pragma unroll
            for (int kk = 0; kk < 2; ++kk) {
                const int sl = (kk * 4 + lk) ^ (r & 7);
                bfr[n][kk] = *reinterpret_cast<const bf16x8*>(&Bl[bi][r * 64 + sl * 8]);
            }
        }
        #pragma unroll
        for (int kk = 0; kk < 2; ++kk)
            #pragma unroll
            for (int m = 0; m < MFR; ++m)
                #pragma unroll
                for (int n = 0; n < NFR; ++n)
                    acc[m][n] = __builtin_amdgcn_mfma_f32_16x16x32_bf16(
                        af[m][kk], bfr[n][kk], acc[m][n], 0, 0, 0);

        __builtin_amdgcn_s_barrier();      // all reads of buf[bi] done
    }

    // epilogue: C/D layout col = lane&15, row = (lane>>4)*4 + i
    #pragma unroll
    for (int m = 0; m < MFR; ++m) {
        #pragma unroll
        for (int n = 0; n < NFR; ++n) {
            int col = col0 + wcol * (NFR * 16) + n * 16 + l15;
            float bv = bias[col];
            #pragma unroll
            for (int i = 0; i < 4; ++i) {
                int row = row0 + wrow * (MFR * 16) + m * 16 + lk * 4 + i;
                float v = acc[m][n][i] + bv;
                if (col < split) {
                    if (BF16OUT)
                        ((unsigned short*)C0v)[(size_t)row * ldc0 + col] = f2bf(v);
                    else
                        ((float*)C0v)[(size_t)row * ldc0 + col] = v;
                } else {
                    float w = SILU1 ? (v / (1.f + __expf(-v))) : v;
                    if (BF16OUT)
                        ((unsigned short*)C1v)[(size_t)row * ldc1 + (col - split)] = f2bf(w);
                    else
                        ((float*)C1v)[(size_t)row * ldc1 + (col - split)] = w;
                }
            }
        }
    }
}

// ---------------------------------------------------------------------------
// Fused middle: depthwise conv(k=3,pad=1 along L) + SiLU + Dp* + LayerNorm(E)
//               + *silu(z)  -> gbuf (bf16, feeds K3).
// Wave-per-row: 64 lanes x 8 contiguous e = 512 = E. 4 rows per block.
// SSM scan output is constant over E (h0=0, input term broadcasts over E),
// so LayerNorm cancels it exactly -> skipped. W_x/b_x/A_log are dead inputs.
// ---------------------------------------------------------------------------
__global__ __launch_bounds__(256) void mid_kernel(
    const unsigned short* __restrict__ x, const unsigned short* __restrict__ zs,
    unsigned short* __restrict__ g,
    const float* __restrict__ conv_w, const float* __restrict__ conv_b,
    const float* __restrict__ Dp, const float* __restrict__ ln_g,
    const float* __restrict__ ln_b)
{
    const int lane = threadIdx.x & 63;
    const int wid  = threadIdx.x >> 6;
    int b = blockIdx.x;
    int cpx = gridDim.x >> 3;
    int lin = (b & 7) * cpx + (b >> 3);       // XCD chunk, aligned with GEMMs
    const int row  = lin * 4 + wid;           // b*L + l
    const int l    = row & (LLEN - 1);
    const int e0   = lane * 8;
    const size_t base = (size_t)row * EE + e0;

    bf16x8 xc = *reinterpret_cast<const bf16x8*>(x + base);
    bf16x8 xm = {}, xp = {};
    if (l > 0)        xm = *reinterpret_cast<const bf16x8*>(x + base - EE);
    if (l < LLEN - 1) xp = *reinterpret_cast<const bf16x8*>(x + base + EE);

    float o[8];
    float s1 = 0.f, s2 = 0.f;
    #pragma unroll
    for (int j = 0; j < 8; ++j) {
        int e = e0 + j;
        float v = conv_b[e]
                + bf2f((unsigned short)xm[j]) * conv_w[e * 3 + 0]
                + bf2f((unsigned short)xc[j]) * conv_w[e * 3 + 1]
                + bf2f((unsigned short)xp[j]) * conv_w[e * 3 + 2];
        float sx = v / (1.f + __expf(-v));   // silu
        float oe = Dp[e] * sx;
        o[j] = oe;
        s1 += oe;
        s2 += oe * oe;
    }

    // full-wave butterfly reduce (all lanes get the sums)
    #pragma unroll
    for (int off = 1; off < 64; off <<= 1) {
        s1 += __shfl_xor(s1, off);
        s2 += __shfl_xor(s2, off);
    }

    const float mu  = s1 * (1.f / EE);
    const float var = s2 * (1.f / EE) - mu * mu;
    const float inv = rsqrtf(var + 1e-5f);

    bf16x8 zv = *reinterpret_cast<const bf16x8*>(zs + base);
    bf16x8 ov;
    #pragma unroll
    for (int j = 0; j < 8; ++j) {
        int e = e0 + j;
        float gy = ((o[j] - mu) * inv * ln_g[e] + ln_b[e]) * bf2f((unsigned short)zv[j]);
        ov[j] = (short)f2bf(gy);
    }
    *reinterpret_cast<bf16x8*>(g + base) = ov;
}

// ---------------------------------------------------------------------------
extern "C" void kernel_launch(void* const* d_in, const int* in_sizes, int n_in,
                              void* d_out, int out_size, void* d_ws, size_t ws_size,
                              hipStream_t stream)
{
    const float* u      = (const float*)d_in[0];
    const float* W_in   = (const float*)d_in[1];
    const float* b_in   = (const float*)d_in[2];
    const float* conv_w = (const float*)d_in[3];
    const float* conv_b = (const float*)d_in[4];
    // d_in[5]=W_x, d_in[6]=b_x, d_in[7]=A_log: dead (scan cancels under LN)
    const float* Dp     = (const float*)d_in[8];
    const float* W_out  = (const float*)d_in[9];
    const float* b_out  = (const float*)d_in[10];
    const float* ln_g   = (const float*)d_in[11];
    const float* ln_b   = (const float*)d_in[12];
    float* out = (float*)d_out;

    // workspace carve-up (all bf16 intermediates)
    char* ws = (char*)d_ws;
    unsigned short* ubf   = (unsigned short*)ws; ws += (size_t)MM * HH * 2;    // 8.4MB
    unsigned short* wtin  = (unsigned short*)ws; ws += (size_t)1024 * HH * 2;  // 0.5MB
    unsigned short* wtout = (unsigned short*)ws; ws += (size_t)HH * EE * 2;    // 0.25MB
    unsigned short* xbuf  = (unsigned short*)ws; ws += (size_t)MM * EE * 2;    // 16.8MB
    unsigned short* zsbuf = (unsigned short*)ws; ws += (size_t)MM * EE * 2;    // 16.8MB  silu(z)
    unsigned short* gbuf  = (unsigned short*)ws;                               // 16.8MB

    dim3 blk(256);

    // prep: casts + weight transposes
    cast_bf16_kernel<<<dim3(MM * HH / 1024), blk, 0, stream>>>(u, ubf);
    transpose_cast_kernel<<<dim3((1024 * HH + 255) / 256), blk, 0, stream>>>(W_in, wtin, HH, 1024);
    transpose_cast_kernel<<<dim3((HH * EE + 255) / 256), blk, 0, stream>>>(W_out, wtout, EE, HH);

    // K1: xz = u @ W_in + b_in ; cols [0,512)->x bf16, [512,1024)->silu(z) bf16
    // tile 128x128, grid 8x128 = 1024 blocks
    gemm2<128, 128, HH, 4, 4, 8, true, true><<<dim3(1024), blk, 0, stream>>>(
        ubf, wtin, b_in, xbuf, zsbuf, EE, EE, EE);

    // K2: conv+silu+Dp*+LN+*silu(z) -> gbuf bf16
    mid_kernel<<<dim3(MM / 4), blk, 0, stream>>>(
        xbuf, zsbuf, gbuf, conv_w, conv_b, Dp, ln_g, ln_b);

    // K3: out = gbuf @ W_out + b_out (f32 out); tile 128x64, grid 4x128 = 512
    gemm2<128, 64, EE, 4, 2, 4, false, false><<<dim3(512), blk, 0, stream>>>(
        gbuf, wtout, b_out, out, out, 1 << 30, HH, HH);
}